// Round 11
// baseline (552.117 us; speedup 1.0000x reference)
//
#include <hip/hip_runtime.h>
#include <hip/hip_bf16.h>

#define B 4
#define S 2048
#define D 512
#define P 16
#define NC 64   // chunks over sequence
#define CL 32   // chunk length = S/NC
#define REP 16  // attribution probe: repeat each kernel body 16x

// opaque zero: compiler cannot prove it is 0, so repeated bodies can't be CSE'd
__device__ __forceinline__ int opaque_zero() {
    int z;
    asm volatile("v_mov_b32 %0, 0" : "=v"(z));
    return z;
}

// ---------------------------------------------------------------------------
// Kernel 1 (R10 body x REP): prods + softmax. One wave per 4 rows, proxy
// hoisted to VGPRs, merge-tree reduction.
// ---------------------------------------------------------------------------
__global__ __launch_bounds__(256) void k_prods(const float* __restrict__ x,
                                               const float* __restrict__ proxy,
                                               float* __restrict__ prods,
                                               float* __restrict__ wgt) {
    const int wave = (blockIdx.x * blockDim.x + threadIdx.x) >> 6;
    const int lane = threadIdx.x & 63;
    const int bs0  = wave * 4;

#pragma unroll 1
    for (int rep = 0; rep < REP; ++rep) {
        const int z = opaque_zero();
        const float* xz = x + z;
        const float* pz = proxy + z;

        float4 pA[P], pB[P];
#pragma unroll
        for (int p = 0; p < P; ++p) {
            const float* pr = pz + p * D + lane * 8;
            pA[p] = *(const float4*)pr;
            pB[p] = *(const float4*)(pr + 4);
        }

#pragma unroll
        for (int r = 0; r < 4; ++r) {
            const int bs = bs0 + r;
            const float* xr = xz + (size_t)bs * D + lane * 8;
            float4 xa = *(const float4*)xr;
            float4 xb = *(const float4*)(xr + 4);

            float part[P];
#pragma unroll
            for (int p = 0; p < P; ++p) {
                part[p] = xa.x*pA[p].x + xa.y*pA[p].y + xa.z*pA[p].z + xa.w*pA[p].w
                        + xb.x*pB[p].x + xb.y*pB[p].y + xb.z*pB[p].z + xb.w*pB[p].w;
            }

            float a8[8];
#pragma unroll
            for (int k = 0; k < 8; ++k) {
                bool hi = lane & 1;
                float mine = hi ? part[2*k+1] : part[2*k];
                float oth  = hi ? part[2*k]   : part[2*k+1];
                a8[k] = mine + __shfl_xor(oth, 1);
            }
            float a4[4];
#pragma unroll
            for (int k = 0; k < 4; ++k) {
                bool hi = lane & 2;
                float mine = hi ? a8[2*k+1] : a8[2*k];
                float oth  = hi ? a8[2*k]   : a8[2*k+1];
                a4[k] = mine + __shfl_xor(oth, 2);
            }
            float a2[2];
#pragma unroll
            for (int k = 0; k < 2; ++k) {
                bool hi = lane & 4;
                float mine = hi ? a4[2*k+1] : a4[2*k];
                float oth  = hi ? a4[2*k]   : a4[2*k+1];
                a2[k] = mine + __shfl_xor(oth, 4);
            }
            float a1;
            {
                bool hi = lane & 8;
                float mine = hi ? a2[1] : a2[0];
                float oth  = hi ? a2[0] : a2[1];
                a1 = mine + __shfl_xor(oth, 8);
            }
            a1 += __shfl_xor(a1, 16);
            a1 += __shfl_xor(a1, 32);

            float m = a1;
#pragma unroll
            for (int off = 1; off < 16; off <<= 1) m = fmaxf(m, __shfl_xor(m, off));
            float e = __expf((a1 - m) * 0.25f);
            float den = e;
#pragma unroll
            for (int off = 1; off < 16; off <<= 1) den += __shfl_xor(den, off);

            if (lane < P) {
                prods[(size_t)bs * P + lane] = a1;
                wgt  [(size_t)bs * P + lane] = e / den;
            }
        }
    }
}

// ---------------------------------------------------------------------------
// Kernel 2 (R4 body x REP): chunk totals. Block = (b,c,half).
// ---------------------------------------------------------------------------
__global__ __launch_bounds__(256) void k_totals(const float* __restrict__ x,
                                                const float* __restrict__ prods,
                                                float* __restrict__ T) {
    int h = blockIdx.x & 1;
    int c = (blockIdx.x >> 1) & (NC - 1);
    int b = blockIdx.x >> 7;
    int d = h * 256 + threadIdx.x;
    int bs0 = b * S + c * CL;

#pragma unroll 1
    for (int rep = 0; rep < REP; ++rep) {
        const int z = opaque_zero();
        const float* xv_base = x + z;
        const float* pr_base = prods + z;

        float acc[P];
#pragma unroll
        for (int p = 0; p < P; ++p) acc[p] = 0.f;

#pragma unroll 4
        for (int i = 0; i < CL; ++i) {
            int bs = bs0 + i;
            float xv = xv_base[(size_t)bs * D + d];
            const float4* pp = (const float4*)(pr_base + (size_t)bs * P);
            float pr[P];
            ((float4*)pr)[0] = pp[0];
            ((float4*)pr)[1] = pp[1];
            ((float4*)pr)[2] = pp[2];
            ((float4*)pr)[3] = pp[3];
#pragma unroll
            for (int p = 0; p < P; ++p) acc[p] = fmaf(pr[p], xv, acc[p]);
        }
        size_t tb = ((size_t)(b * NC + c)) * (P * D) + d;
#pragma unroll
        for (int p = 0; p < P; ++p) T[tb + p * D] = acc[p];
    }
}

// ---------------------------------------------------------------------------
// Kernel 3 (R4 body x REP): exclusive prefix over chunks. Non-destructive
// into T2 for reps 0..REP-2, final rep in place (same result as R10).
// ---------------------------------------------------------------------------
__global__ __launch_bounds__(256) void k_scan(float* __restrict__ T,
                                              float* __restrict__ T2) {
    int t = blockIdx.x * blockDim.x + threadIdx.x;
    int d = t & (D - 1);
    int p = (t >> 9) & (P - 1);
    int b = t >> 13;
    size_t base = ((size_t)b * NC * P + p) * D + d;

#pragma unroll 1
    for (int rep = 0; rep < REP; ++rep) {
        const int z = opaque_zero();
        const float* src = T + z;
        float* dst = (rep == REP - 1) ? T : T2;
        float run = 0.f;
#pragma unroll 8
        for (int c = 0; c < NC; ++c) {
            size_t idx = base + (size_t)c * (P * D);
            float v = src[idx];
            dst[idx] = run;
            run += v;
        }
    }
}

// ---------------------------------------------------------------------------
// Kernel 4 (R4 body x REP): apply. Block = (b,c,half).
// ---------------------------------------------------------------------------
__global__ __launch_bounds__(256) void k_apply(const float* __restrict__ x,
                                               const float* __restrict__ prods,
                                               const float* __restrict__ wgt,
                                               const float* __restrict__ T,
                                               float* __restrict__ out) {
    int h = blockIdx.x & 1;
    int c = (blockIdx.x >> 1) & (NC - 1);
    int b = blockIdx.x >> 7;
    int d = h * 256 + threadIdx.x;
    int bs0 = b * S + c * CL;

#pragma unroll 1
    for (int rep = 0; rep < REP; ++rep) {
        const int z = opaque_zero();
        const float* xb2 = x + z;
        const float* prb = prods + z;
        const float* wwb = wgt + z;

        float st[P];
        size_t tb = ((size_t)(b * NC + c)) * (P * D) + d;
#pragma unroll
        for (int p = 0; p < P; ++p) st[p] = T[tb + p * D];

#pragma unroll 2
        for (int i = 0; i < CL; ++i) {
            int bs = bs0 + i;
            float xv = xb2[(size_t)bs * D + d];
            const float4* pp = (const float4*)(prb + (size_t)bs * P);
            const float4* wp = (const float4*)(wwb + (size_t)bs * P);
            float pr[P], ww[P];
            ((float4*)pr)[0] = pp[0];
            ((float4*)pr)[1] = pp[1];
            ((float4*)pr)[2] = pp[2];
            ((float4*)pr)[3] = pp[3];
            ((float4*)ww)[0] = wp[0];
            ((float4*)ww)[1] = wp[1];
            ((float4*)ww)[2] = wp[2];
            ((float4*)ww)[3] = wp[3];
            float o = 0.f;
#pragma unroll
            for (int p = 0; p < P; ++p) {
                st[p] = fmaf(pr[p], xv, st[p]);
                o = fmaf(ww[p], st[p], o);
            }
            out[(size_t)bs * D + d] = o;
        }
    }
}

extern "C" void kernel_launch(void* const* d_in, const int* in_sizes, int n_in,
                              void* d_out, int out_size, void* d_ws, size_t ws_size,
                              hipStream_t stream) {
    const float* x     = (const float*)d_in[0];
    const float* proxy = (const float*)d_in[1];
    float* out   = (float*)d_out;

    float* prods = (float*)d_ws;                 // B*S*P floats = 512 KiB
    float* wgt   = prods + (size_t)B * S * P;    // 512 KiB
    float* T     = wgt   + (size_t)B * S * P;    // 8 MiB
    float* T2    = T     + (size_t)B * NC * P * D; // 8 MiB scan scratch (probe only)

    k_prods <<<(B * S) / 4 / 4,   256, 0, stream>>>(x, proxy, prods, wgt);
    k_totals<<<B * NC * 2,        256, 0, stream>>>(x, prods, T);
    k_scan  <<<(B * P * D) / 256, 256, 0, stream>>>(T, T2);
    k_apply <<<B * NC * 2,        256, 0, stream>>>(x, prods, wgt, T, out);
}

// Round 12
// 44.146 us; speedup vs baseline: 12.5066x; 12.5066x over previous
//
#include <hip/hip_runtime.h>
#include <hip/hip_bf16.h>

#define B 4
#define S 2048
#define D 512
#define P 16
#define NC 128  // chunks over sequence (was 64)
#define CL 16   // chunk length = S/NC

// ---------------------------------------------------------------------------
// Kernel 1: prods + softmax (R10 verbatim). One wave per 4 rows, proxy
// hoisted to VGPRs, merge-tree reduction.
// ---------------------------------------------------------------------------
__global__ __launch_bounds__(256) void k_prods(const float* __restrict__ x,
                                               const float* __restrict__ proxy,
                                               float* __restrict__ prods,
                                               float* __restrict__ wgt) {
    const int wave = (blockIdx.x * blockDim.x + threadIdx.x) >> 6;  // 0..2047
    const int lane = threadIdx.x & 63;
    const int bs0  = wave * 4;

    float4 pA[P], pB[P];
#pragma unroll
    for (int p = 0; p < P; ++p) {
        const float* pr = proxy + p * D + lane * 8;
        pA[p] = *(const float4*)pr;
        pB[p] = *(const float4*)(pr + 4);
    }

#pragma unroll
    for (int r = 0; r < 4; ++r) {
        const int bs = bs0 + r;
        const float* xr = x + (size_t)bs * D + lane * 8;
        float4 xa = *(const float4*)xr;
        float4 xb = *(const float4*)(xr + 4);

        float part[P];
#pragma unroll
        for (int p = 0; p < P; ++p) {
            part[p] = xa.x*pA[p].x + xa.y*pA[p].y + xa.z*pA[p].z + xa.w*pA[p].w
                    + xb.x*pB[p].x + xb.y*pB[p].y + xb.z*pB[p].z + xb.w*pB[p].w;
        }

        float a8[8];
#pragma unroll
        for (int k = 0; k < 8; ++k) {
            bool hi = lane & 1;
            float mine = hi ? part[2*k+1] : part[2*k];
            float oth  = hi ? part[2*k]   : part[2*k+1];
            a8[k] = mine + __shfl_xor(oth, 1);
        }
        float a4[4];
#pragma unroll
        for (int k = 0; k < 4; ++k) {
            bool hi = lane & 2;
            float mine = hi ? a8[2*k+1] : a8[2*k];
            float oth  = hi ? a8[2*k]   : a8[2*k+1];
            a4[k] = mine + __shfl_xor(oth, 2);
        }
        float a2[2];
#pragma unroll
        for (int k = 0; k < 2; ++k) {
            bool hi = lane & 4;
            float mine = hi ? a4[2*k+1] : a4[2*k];
            float oth  = hi ? a4[2*k]   : a4[2*k+1];
            a2[k] = mine + __shfl_xor(oth, 4);
        }
        float a1;
        {
            bool hi = lane & 8;
            float mine = hi ? a2[1] : a2[0];
            float oth  = hi ? a2[0] : a2[1];
            a1 = mine + __shfl_xor(oth, 8);
        }
        a1 += __shfl_xor(a1, 16);
        a1 += __shfl_xor(a1, 32);

        float m = a1;
#pragma unroll
        for (int off = 1; off < 16; off <<= 1) m = fmaxf(m, __shfl_xor(m, off));
        float e = __expf((a1 - m) * 0.25f);
        float den = e;
#pragma unroll
        for (int off = 1; off < 16; off <<= 1) den += __shfl_xor(den, off);

        if (lane < P) {
            prods[(size_t)bs * P + lane] = a1;
            wgt  [(size_t)bs * P + lane] = e / den;
        }
    }
}

// ---------------------------------------------------------------------------
// Kernel 2: chunk totals T[b,c,p,d] (R4 body; CL=16, grid 1024 -> 4 blk/CU).
// ---------------------------------------------------------------------------
__global__ __launch_bounds__(256) void k_totals(const float* __restrict__ x,
                                                const float* __restrict__ prods,
                                                float* __restrict__ T) {
    int h = blockIdx.x & 1;
    int c = (blockIdx.x >> 1) & (NC - 1);
    int b = blockIdx.x >> 8;
    int d = h * 256 + threadIdx.x;

    float acc[P];
#pragma unroll
    for (int p = 0; p < P; ++p) acc[p] = 0.f;

    int bs0 = b * S + c * CL;
#pragma unroll 4
    for (int i = 0; i < CL; ++i) {
        int bs = bs0 + i;
        float xv = x[(size_t)bs * D + d];
        const float4* pp = (const float4*)(prods + (size_t)bs * P);
        float pr[P];
        ((float4*)pr)[0] = pp[0];
        ((float4*)pr)[1] = pp[1];
        ((float4*)pr)[2] = pp[2];
        ((float4*)pr)[3] = pp[3];
#pragma unroll
        for (int p = 0; p < P; ++p) acc[p] = fmaf(pr[p], xv, acc[p]);
    }
    size_t tb = ((size_t)(b * NC + c)) * (P * D) + d;
#pragma unroll
    for (int p = 0; p < P; ++p) T[tb + p * D] = acc[p];
}

// ---------------------------------------------------------------------------
// Kernel 3: exclusive prefix over 128 chunks, segmented. Block = (b,p,dgrp):
// 512 blocks x 256 threads; thread = (64-d-slice, segment g of 4). Each
// thread scans 32 chunks held in registers; segment totals cross via LDS.
// ---------------------------------------------------------------------------
__global__ __launch_bounds__(256) void k_scan(float* __restrict__ T) {
    __shared__ float s_tot[4][64];

    const int dgrp = blockIdx.x & 7;
    const int p    = (blockIdx.x >> 3) & 15;
    const int b    = blockIdx.x >> 7;
    const int dl   = threadIdx.x & 63;
    const int g    = threadIdx.x >> 6;          // segment 0..3
    const int d    = dgrp * 64 + dl;

    const size_t chunk_stride = (size_t)P * D;
    const size_t base = ((size_t)b * NC * P + p) * D + d + (size_t)(g * 32) * chunk_stride;

    float v[32];
#pragma unroll 8
    for (int c = 0; c < 32; ++c) v[c] = T[base + (size_t)c * chunk_stride];

    float tot = 0.f;
#pragma unroll
    for (int c = 0; c < 32; ++c) tot += v[c];

    s_tot[g][dl] = tot;
    __syncthreads();

    float run = 0.f;
#pragma unroll
    for (int gg = 0; gg < 3; ++gg)
        if (gg < g) run += s_tot[gg][dl];

    #pragma unroll 8
    for (int c = 0; c < 32; ++c) {
        T[base + (size_t)c * chunk_stride] = run;
        run += v[c];
    }
}

// ---------------------------------------------------------------------------
// Kernel 4: apply (R4 body; CL=16, grid 1024 -> 4 blk/CU).
// ---------------------------------------------------------------------------
__global__ __launch_bounds__(256) void k_apply(const float* __restrict__ x,
                                               const float* __restrict__ prods,
                                               const float* __restrict__ wgt,
                                               const float* __restrict__ T,
                                               float* __restrict__ out) {
    int h = blockIdx.x & 1;
    int c = (blockIdx.x >> 1) & (NC - 1);
    int b = blockIdx.x >> 8;
    int d = h * 256 + threadIdx.x;

    float st[P];
    size_t tb = ((size_t)(b * NC + c)) * (P * D) + d;
#pragma unroll
    for (int p = 0; p < P; ++p) st[p] = T[tb + p * D];

    int bs0 = b * S + c * CL;
#pragma unroll 2
    for (int i = 0; i < CL; ++i) {
        int bs = bs0 + i;
        float xv = x[(size_t)bs * D + d];
        const float4* pp = (const float4*)(prods + (size_t)bs * P);
        const float4* wp = (const float4*)(wgt   + (size_t)bs * P);
        float pr[P], ww[P];
        ((float4*)pr)[0] = pp[0];
        ((float4*)pr)[1] = pp[1];
        ((float4*)pr)[2] = pp[2];
        ((float4*)pr)[3] = pp[3];
        ((float4*)ww)[0] = wp[0];
        ((float4*)ww)[1] = wp[1];
        ((float4*)ww)[2] = wp[2];
        ((float4*)ww)[3] = wp[3];
        float o = 0.f;
#pragma unroll
        for (int p = 0; p < P; ++p) {
            st[p] = fmaf(pr[p], xv, st[p]);
            o = fmaf(ww[p], st[p], o);
        }
        out[(size_t)bs * D + d] = o;
    }
}

extern "C" void kernel_launch(void* const* d_in, const int* in_sizes, int n_in,
                              void* d_out, int out_size, void* d_ws, size_t ws_size,
                              hipStream_t stream) {
    const float* x     = (const float*)d_in[0];
    const float* proxy = (const float*)d_in[1];
    float* out   = (float*)d_out;

    float* prods = (float*)d_ws;                 // B*S*P floats = 512 KiB
    float* wgt   = prods + (size_t)B * S * P;    // 512 KiB
    float* T     = wgt   + (size_t)B * S * P;    // B*NC*P*D floats = 16 MiB

    k_prods <<<(B * S) / 16,  256, 0, stream>>>(x, proxy, prods, wgt);
    k_totals<<<B * NC * 2,    256, 0, stream>>>(x, prods, T);
    k_scan  <<<B * P * 8,     256, 0, stream>>>(T);
    k_apply <<<B * NC * 2,    256, 0, stream>>>(x, prods, wgt, T, out);
}

// Round 13
// 35.756 us; speedup vs baseline: 15.4413x; 1.2347x over previous
//
#include <hip/hip_runtime.h>
#include <hip/hip_bf16.h>

#define B 4
#define S 2048
#define D 512
#define P 16
#define NC 64   // chunks over sequence
#define CL 32   // chunk length = S/NC

// ---------------------------------------------------------------------------
// Kernel 1: prods + softmax (R10 verbatim). One wave per 4 rows, proxy
// hoisted to VGPRs, merge-tree reduction.
// ---------------------------------------------------------------------------
__global__ __launch_bounds__(256) void k_prods(const float* __restrict__ x,
                                               const float* __restrict__ proxy,
                                               float* __restrict__ prods,
                                               float* __restrict__ wgt) {
    const int wave = (blockIdx.x * blockDim.x + threadIdx.x) >> 6;  // 0..2047
    const int lane = threadIdx.x & 63;
    const int bs0  = wave * 4;

    float4 pA[P], pB[P];
#pragma unroll
    for (int p = 0; p < P; ++p) {
        const float* pr = proxy + p * D + lane * 8;
        pA[p] = *(const float4*)pr;
        pB[p] = *(const float4*)(pr + 4);
    }

#pragma unroll
    for (int r = 0; r < 4; ++r) {
        const int bs = bs0 + r;
        const float* xr = x + (size_t)bs * D + lane * 8;
        float4 xa = *(const float4*)xr;
        float4 xb = *(const float4*)(xr + 4);

        float part[P];
#pragma unroll
        for (int p = 0; p < P; ++p) {
            part[p] = xa.x*pA[p].x + xa.y*pA[p].y + xa.z*pA[p].z + xa.w*pA[p].w
                    + xb.x*pB[p].x + xb.y*pB[p].y + xb.z*pB[p].z + xb.w*pB[p].w;
        }

        float a8[8];
#pragma unroll
        for (int k = 0; k < 8; ++k) {
            bool hi = lane & 1;
            float mine = hi ? part[2*k+1] : part[2*k];
            float oth  = hi ? part[2*k]   : part[2*k+1];
            a8[k] = mine + __shfl_xor(oth, 1);
        }
        float a4[4];
#pragma unroll
        for (int k = 0; k < 4; ++k) {
            bool hi = lane & 2;
            float mine = hi ? a8[2*k+1] : a8[2*k];
            float oth  = hi ? a8[2*k]   : a8[2*k+1];
            a4[k] = mine + __shfl_xor(oth, 2);
        }
        float a2[2];
#pragma unroll
        for (int k = 0; k < 2; ++k) {
            bool hi = lane & 4;
            float mine = hi ? a4[2*k+1] : a4[2*k];
            float oth  = hi ? a4[2*k]   : a4[2*k+1];
            a2[k] = mine + __shfl_xor(oth, 4);
        }
        float a1;
        {
            bool hi = lane & 8;
            float mine = hi ? a2[1] : a2[0];
            float oth  = hi ? a2[0] : a2[1];
            a1 = mine + __shfl_xor(oth, 8);
        }
        a1 += __shfl_xor(a1, 16);
        a1 += __shfl_xor(a1, 32);

        float m = a1;
#pragma unroll
        for (int off = 1; off < 16; off <<= 1) m = fmaxf(m, __shfl_xor(m, off));
        float e = __expf((a1 - m) * 0.25f);
        float den = e;
#pragma unroll
        for (int off = 1; off < 16; off <<= 1) den += __shfl_xor(den, off);

        if (lane < P) {
            prods[(size_t)bs * P + lane] = a1;
            wgt  [(size_t)bs * P + lane] = e / den;
        }
    }
}

// ---------------------------------------------------------------------------
// Kernel 2: chunk totals T[b,c,p,d] (R10 verbatim). Block = (b,c,half).
// ---------------------------------------------------------------------------
__global__ __launch_bounds__(256) void k_totals(const float* __restrict__ x,
                                                const float* __restrict__ prods,
                                                float* __restrict__ T) {
    int h = blockIdx.x & 1;
    int c = (blockIdx.x >> 1) & (NC - 1);
    int b = blockIdx.x >> 7;
    int d = h * 256 + threadIdx.x;

    float acc[P];
#pragma unroll
    for (int p = 0; p < P; ++p) acc[p] = 0.f;

    int bs0 = b * S + c * CL;
#pragma unroll 4
    for (int i = 0; i < CL; ++i) {
        int bs = bs0 + i;
        float xv = x[(size_t)bs * D + d];
        const float4* pp = (const float4*)(prods + (size_t)bs * P);
        float pr[P];
        ((float4*)pr)[0] = pp[0];
        ((float4*)pr)[1] = pp[1];
        ((float4*)pr)[2] = pp[2];
        ((float4*)pr)[3] = pp[3];
#pragma unroll
        for (int p = 0; p < P; ++p) acc[p] = fmaf(pr[p], xv, acc[p]);
    }
    size_t tb = ((size_t)(b * NC + c)) * (P * D) + d;
#pragma unroll
    for (int p = 0; p < P; ++p) T[tb + p * D] = acc[p];
}

// ---------------------------------------------------------------------------
// Kernel 3: in-place exclusive prefix over chunks (R10 verbatim).
// ---------------------------------------------------------------------------
__global__ __launch_bounds__(256) void k_scan(float* __restrict__ T) {
    int t = blockIdx.x * blockDim.x + threadIdx.x;   // ((b*P+p)*D + d)
    int d = t & (D - 1);
    int p = (t >> 9) & (P - 1);
    int b = t >> 13;
    size_t base = ((size_t)b * NC * P + p) * D + d;
    float run = 0.f;
#pragma unroll 8
    for (int c = 0; c < NC; ++c) {
        size_t idx = base + (size_t)c * (P * D);
        float v = T[idx];
        T[idx] = run;
        run += v;
    }
}

// ---------------------------------------------------------------------------
// Kernel 4: apply. Block = (b,c,half), 256 threads, thread = d within half.
// NEW: (a) chunk's prods/wgt staged to LDS once (coalesced float4), inner
// loop reads them as uniform-address ds_read_b128 broadcasts (no SGPR
// pressure, ~60cy latency); (b) all 32 x-row loads preloaded to VGPRs
// up-front (safe now that no scalar-load path exists to blow up).
// Same FMA order as R10 -> bit-identical output.
// ---------------------------------------------------------------------------
__global__ __launch_bounds__(256) void k_apply(const float* __restrict__ x,
                                               const float* __restrict__ prods,
                                               const float* __restrict__ wgt,
                                               const float* __restrict__ T,
                                               float* __restrict__ out) {
    __shared__ float s_pw[2][CL][P];    // [0]=prods, [1]=wgt : 4 KiB

    int h = blockIdx.x & 1;
    int c = (blockIdx.x >> 1) & (NC - 1);
    int b = blockIdx.x >> 7;
    int d = h * 256 + threadIdx.x;
    int bs0 = b * S + c * CL;

    // cooperative stage: 1024 floats = 256 float4s; thread t loads one.
    {
        int t = threadIdx.x;
        if (t < 128) {
            ((float4*)&s_pw[0][0][0])[t] =
                ((const float4*)(prods + (size_t)bs0 * P))[t];
        } else {
            ((float4*)&s_pw[1][0][0])[t - 128] =
                ((const float4*)(wgt + (size_t)bs0 * P))[t - 128];
        }
    }

    // x rows preloaded (VGPR only; issues 32 independent loads)
    float xv[CL];
#pragma unroll
    for (int i = 0; i < CL; ++i) xv[i] = x[(size_t)(bs0 + i) * D + d];

    float st[P];
    size_t tb = ((size_t)(b * NC + c)) * (P * D) + d;
#pragma unroll
    for (int p = 0; p < P; ++p) st[p] = T[tb + p * D];

    __syncthreads();

#pragma unroll
    for (int i = 0; i < CL; ++i) {
        float pr[P], ww[P];
        const float4* sp = (const float4*)&s_pw[0][i][0];
        const float4* sw = (const float4*)&s_pw[1][i][0];
        ((float4*)pr)[0] = sp[0];
        ((float4*)pr)[1] = sp[1];
        ((float4*)pr)[2] = sp[2];
        ((float4*)pr)[3] = sp[3];
        ((float4*)ww)[0] = sw[0];
        ((float4*)ww)[1] = sw[1];
        ((float4*)ww)[2] = sw[2];
        ((float4*)ww)[3] = sw[3];
        float o = 0.f;
#pragma unroll
        for (int p = 0; p < P; ++p) {
            st[p] = fmaf(pr[p], xv[i], st[p]);
            o = fmaf(ww[p], st[p], o);
        }
        out[(size_t)(bs0 + i) * D + d] = o;
    }
}

extern "C" void kernel_launch(void* const* d_in, const int* in_sizes, int n_in,
                              void* d_out, int out_size, void* d_ws, size_t ws_size,
                              hipStream_t stream) {
    const float* x     = (const float*)d_in[0];
    const float* proxy = (const float*)d_in[1];
    float* out   = (float*)d_out;

    float* prods = (float*)d_ws;                 // B*S*P floats = 512 KiB
    float* wgt   = prods + (size_t)B * S * P;    // 512 KiB
    float* T     = wgt   + (size_t)B * S * P;    // B*NC*P*D floats = 8 MiB

    k_prods <<<(B * S) / 16,      256, 0, stream>>>(x, proxy, prods, wgt);
    k_totals<<<B * NC * 2,        256, 0, stream>>>(x, prods, T);
    k_scan  <<<(B * P * D) / 256, 256, 0, stream>>>(T);
    k_apply <<<B * NC * 2,        256, 0, stream>>>(x, prods, wgt, T, out);
}